// Round 4
// baseline (11153.557 us; speedup 1.0000x reference)
//
#include <hip/hip_runtime.h>

// LSTM_88776974008866: bidirectional LSTM (B=2048, S=128, H=512, in=4) + 4 sigmoid heads.
// Round 4: persistent cooperative kernel with per-producer dataflow flags instead of a
// group barrier; x*Wih + bias folded into a K=32 tail MFMA; W stationary in LDS
// (fragment-contiguous, conflict-free); c in registers; setprio around MFMA clusters.

typedef __attribute__((ext_vector_type(8))) __bf16 bf16x8;
typedef __attribute__((ext_vector_type(4))) float f32x4;
typedef __attribute__((ext_vector_type(8))) unsigned short u16x8;

__device__ __forceinline__ unsigned short f2bf(float f) {
  unsigned u = __float_as_uint(f);
  u += 0x7fffu + ((u >> 16) & 1u);   // round-to-nearest-even
  return (unsigned short)(u >> 16);
}
__device__ __forceinline__ float bf2f(unsigned short s) {
  return __uint_as_float(((unsigned)s) << 16);
}
__device__ __forceinline__ float sigm(float x) { return 1.0f / (1.0f + __expf(-x)); }
__device__ __forceinline__ float tanhfast(float x) {
  float e = __expf(-2.0f * fabsf(x));
  float t = (1.0f - e) / (1.0f + e);
  return x < 0.0f ? -t : t;
}

__device__ __forceinline__ void gl_lds16(const void* g, void* l) {
  __builtin_amdgcn_global_load_lds(
      (const __attribute__((address_space(1))) unsigned int*)g,
      (__attribute__((address_space(3))) unsigned int*)l, 16, 0, 0);
}

// ---------------------------------------------------------------------------
// prep: Whh (fp32 [2048][512], gate-major rows i,f,g,o) -> Wp fragment image:
//   chunk = ((((dir*16+ni)*2+wn)*16+kt)*4+nf)*64 + lhi*16 + l15   (16B chunks)
// Also wtail[dir][permrow][8] = {wih[0..3], bias, 0,0,0} in bf16 for the tail MFMA.
// ---------------------------------------------------------------------------
__global__ __launch_bounds__(256) void prep_k(
    const float* __restrict__ Wf_hh, const float* __restrict__ Wf_ih,
    const float* __restrict__ bf_ih, const float* __restrict__ bf_hh,
    const float* __restrict__ Wb_hh, const float* __restrict__ Wb_ih,
    const float* __restrict__ bb_ih, const float* __restrict__ bb_hh,
    unsigned short* __restrict__ Wp, unsigned short* __restrict__ wtailp)
{
  int flat = blockIdx.x * 256 + threadIdx.x;   // 0 .. 262143
  int l15 = flat & 15;
  int lhi = (flat >> 4) & 3;
  int nf  = (flat >> 6) & 3;
  int kt  = (flat >> 8) & 15;
  int wn  = (flat >> 12) & 1;
  int ni  = (flat >> 13) & 15;
  int dir = (flat >> 17) & 1;
  const float* Whh = dir ? Wb_hh : Wf_hh;
  const float* Wih = dir ? Wb_ih : Wf_ih;
  const float* bih = dir ? bb_ih : bf_ih;
  const float* bhh = dir ? bb_hh : bf_hh;

  int j = ((ni * 2 + wn) << 4) + l15;          // hidden index 0..511
  int orig = (nf << 9) + j;                    // original gate-major row
  int k0 = (kt << 5) + (lhi << 3);
  const float4* src = (const float4*)(Whh + (size_t)orig * 512 + k0);
  float4 a = src[0], b = src[1];
  u16x8 o;
  o[0] = f2bf(a.x); o[1] = f2bf(a.y); o[2] = f2bf(a.z); o[3] = f2bf(a.w);
  o[4] = f2bf(b.x); o[5] = f2bf(b.y); o[6] = f2bf(b.z); o[7] = f2bf(b.w);
  *(u16x8*)(Wp + (size_t)flat * 8) = o;

  if (kt == 0 && lhi == 0) {
    int rg = (ni << 7) + (wn << 6) + (nf << 4) + l15;   // permuted row
    unsigned short* wt = wtailp + (((size_t)(dir << 11) + rg) << 3);
    wt[0] = f2bf(Wih[orig * 4 + 0]);
    wt[1] = f2bf(Wih[orig * 4 + 1]);
    wt[2] = f2bf(Wih[orig * 4 + 2]);
    wt[3] = f2bf(Wih[orig * 4 + 3]);
    wt[4] = f2bf(bih[orig] + bhh[orig]);
    wt[5] = 0; wt[6] = 0; wt[7] = 0;
  }
}

__device__ __forceinline__ void mfma16(const bf16x8 av[4], const bf16x8 bv[4],
                                       f32x4 acc[4][4]) {
#pragma unroll
  for (int mf = 0; mf < 4; ++mf)
#pragma unroll
    for (int nf = 0; nf < 4; ++nf)
      acc[mf][nf] = __builtin_amdgcn_mfma_f32_16x16x32_bf16(av[mf], bv[nf], acc[mf][nf], 0, 0, 0);
}

// ---------------------------------------------------------------------------
// Persistent kernel: 256 blocks x 512 threads (1 block/CU), all 128 timesteps.
// bid = mi + 8*(dir*16 + ni): xcd = bid%8 = mi, so each (mi,dir) group of 16
// blocks (producers AND consumers of h-panel mi) is XCD-local.
// k-slice kt of the A panel is produced by block ni==kt of the same group;
// consumers poll per-slice single-writer flags (dataflow, no barrier).
// ---------------------------------------------------------------------------
__global__ __launch_bounds__(512, 2) void lstm_persist(
    const float* __restrict__ y,
    const unsigned short* __restrict__ Wp,
    const unsigned short* __restrict__ wtailp,
    unsigned short* __restrict__ hf0, unsigned short* __restrict__ hf1,
    unsigned short* __restrict__ hb0, unsigned short* __restrict__ hb1,
    unsigned* __restrict__ prodf)
{
  __shared__ alignas(16) unsigned short Wl[65536];   // 128 KB W image

  const int tid = threadIdx.x;
  const int w = tid >> 6, lane = tid & 63;
  const int bid = blockIdx.x;
  const int mi = bid & 7;
  const int qd = bid >> 3;
  const int dir = qd >> 4;
  const int ni = qd & 15;
  const int bm0 = mi << 8;                 // 256 batch rows
  const int grp = (dir << 3) | mi;

  unsigned short* h0 = dir ? hb0 : hf0;
  unsigned short* h1 = dir ? hb1 : hf1;

  const int wm = w >> 1;                   // 0..3: 64-row quarter
  const int wn = w & 1;                    // 0..1: 64-col half
  const int l15 = lane & 15;
  const int lhi = lane >> 4;

  // ---- one-time: copy this block's 128KB W image into LDS (contiguous) ----
  const unsigned short* Wblk = Wp + ((size_t)((dir << 4) | ni) << 16);
#pragma unroll
  for (int i = 0; i < 16; ++i) {
    gl_lds16(Wblk + (size_t)(((i << 9) + tid)) * 8,
             (unsigned short*)Wl + ((i << 12) + (w << 9)));
  }

  // ---- tail B-fragments (wih + bias), register-resident ----
  bf16x8 btail[4];
#pragma unroll
  for (int nf = 0; nf < 4; ++nf) {
    u16x8 wt = *(const u16x8*)(wtailp +
        (((size_t)(dir << 11) + ((ni << 7) | (wn << 6) | (nf << 4) | l15))) * 8);
    u16x8 z = {};
    u16x8 sel = (lhi == 0) ? wt : z;
    btail[nf] = *(bf16x8*)&sel;
  }

  const int j = (((ni << 1) + wn) << 4) + l15;   // hidden index 0..511
  float c_reg[16];
#pragma unroll
  for (int i = 0; i < 16; ++i) c_reg[i] = 0.f;

  const float4* y4 = (const float4*)y;
  unsigned* myflag = prodf + (((grp << 4) | ni) << 5);   // 128B-spaced, single writer

  // LDS B-fragment base for this wave (contiguous 1KB per (kt,nf) read)
  const unsigned short* wB = Wl + (wn << 15) + (lane << 3);

  __syncthreads();   // Wl ready (drains global_load_lds)

  const unsigned short* hin = h0;
  unsigned short* hout = h1;

#pragma unroll 1
  for (int t = 0; t < 128; ++t) {
    const int t_eff = dir ? (127 - t) : t;

    __syncthreads();  // own-slice intra-block visibility (stores drained at t-1 fence)
    // one acquire per step per wave: L1 invalidate so cross-CU h is fresh
    (void)__hip_atomic_load(myflag, __ATOMIC_ACQUIRE, __HIP_MEMORY_SCOPE_AGENT);

    // x for the tail MFMA (row = A-row of this lane), issued early
    float4 xr[4];
#pragma unroll
    for (int mf = 0; mf < 4; ++mf)
      xr[mf] = y4[(size_t)(bm0 + (wm << 6) + (mf << 4) + l15) * 128 + t_eff];

    // A bases (per mf), imm offsets cover kt*64B
    const unsigned short* aBase = hin + ((size_t)(bm0 + (wm << 6) + l15) << 9) + (lhi << 3);
    const bf16x8* aBm0 = (const bf16x8*)(aBase);
    const bf16x8* aBm1 = (const bf16x8*)(aBase + (16 << 9));
    const bf16x8* aBm2 = (const bf16x8*)(aBase + (32 << 9));
    const bf16x8* aBm3 = (const bf16x8*)(aBase + (48 << 9));

    f32x4 acc[4][4];
#pragma unroll
    for (int a = 0; a < 4; ++a)
#pragma unroll
      for (int b = 0; b < 4; ++b) acc[a][b] = (f32x4){0.f, 0.f, 0.f, 0.f};

    bf16x8 aA[2][4], bT[2][4];

#define POLL(kk)                                                               \
    do { if (t) {                                                              \
      const unsigned* fp_ = prodf + (((grp << 4) | (kk)) << 5);                \
      unsigned v_;                                                             \
      do { v_ = __hip_atomic_load(fp_, __ATOMIC_RELAXED,                       \
                                  __HIP_MEMORY_SCOPE_AGENT); }                 \
      while (v_ < (unsigned)t);                                                \
      asm volatile("" ::: "memory");                                           \
    } } while (0)

#define LOADS(kk, sl)                                                          \
    do {                                                                       \
      aA[sl][0] = aBm0[(kk) * 4];                                              \
      aA[sl][1] = aBm1[(kk) * 4];                                              \
      aA[sl][2] = aBm2[(kk) * 4];                                              \
      aA[sl][3] = aBm3[(kk) * 4];                                              \
      bT[sl][0] = *(const bf16x8*)(wB + ((kk) << 11));                         \
      bT[sl][1] = *(const bf16x8*)(wB + ((kk) << 11) + 512);                   \
      bT[sl][2] = *(const bf16x8*)(wB + ((kk) << 11) + 1024);                  \
      bT[sl][3] = *(const bf16x8*)(wB + ((kk) << 11) + 1536);                  \
    } while (0)

    POLL(0);
    LOADS(0, 0);
#pragma unroll
    for (int i = 0; i < 16; ++i) {
      if (i < 15) {
        POLL(i + 1);
        LOADS(i + 1, (i + 1) & 1);
      }
      __builtin_amdgcn_s_setprio(1);
      mfma16(aA[i & 1], bT[i & 1], acc);
      __builtin_amdgcn_s_setprio(0);
    }
#undef POLL
#undef LOADS

    // ---- tail MFMA: x*Wih + bias via K=32 (only k=0..4 nonzero) ----
    {
      bf16x8 atail[4];
#pragma unroll
      for (int mf = 0; mf < 4; ++mf) {
        u16x8 at = {};
        if (lhi == 0) {
          at[0] = f2bf(xr[mf].x); at[1] = f2bf(xr[mf].y);
          at[2] = f2bf(xr[mf].z); at[3] = f2bf(xr[mf].w);
          at[4] = 0x3F80;   // 1.0 -> picks up bias row
        }
        atail[mf] = *(bf16x8*)&at;
      }
      __builtin_amdgcn_s_setprio(1);
      mfma16(atail, btail, acc);
      __builtin_amdgcn_s_setprio(0);
    }

    // ---- epilogue: lane-local LSTM cell update, c in registers ----
#pragma unroll
    for (int mf = 0; mf < 4; ++mf) {
#pragma unroll
      for (int r = 0; r < 4; ++r) {
        const float ig = sigm(acc[mf][0][r]);
        const float fg = sigm(acc[mf][1][r]);
        const float gg = tanhfast(acc[mf][2][r]);
        const float og = sigm(acc[mf][3][r]);
        const float cn = fg * c_reg[mf * 4 + r] + ig * gg;
        c_reg[mf * 4 + r] = cn;
        const int b = bm0 + (wm << 6) + (mf << 4) + (lhi << 2) + r;
        hout[((size_t)b << 9) + j] = f2bf(og * tanhfast(cn));
      }
    }

    // ---- publish own slice: single-writer release flag ----
    if (t != 127) {
      __threadfence();    // per-wave: drain stores to L2
      __syncthreads();    // all waves' fences complete
      if (tid == 0)
        __hip_atomic_store(myflag, (unsigned)(t + 1), __ATOMIC_RELEASE,
                           __HIP_MEMORY_SCOPE_AGENT);
    }

    const unsigned short* tmp = hin; hin = hout; hout = (unsigned short*)tmp;
  }
}

// ---------------------------------------------------------------------------
// heads: out[b][k] = sigmoid(hf[b]·Wk[0:512] + hb[b]·Wk[512:1024] + bk)
// ---------------------------------------------------------------------------
__global__ __launch_bounds__(256) void heads_k(
    const unsigned short* __restrict__ hf, const unsigned short* __restrict__ hb,
    const float* __restrict__ W1, const float* __restrict__ b1,
    const float* __restrict__ W2, const float* __restrict__ b2,
    const float* __restrict__ W3, const float* __restrict__ b3,
    const float* __restrict__ W4, const float* __restrict__ b4,
    float* __restrict__ out)
{
  const int wid = threadIdx.x >> 6, lane = threadIdx.x & 63;
  const int b = blockIdx.x * 4 + wid;
  const unsigned short* src = (lane < 32) ? (hf + ((size_t)b << 9) + (lane << 4))
                                          : (hb + ((size_t)b << 9) + ((lane - 32) << 4));
  const int woff = lane << 4;
  u16x8 v0 = *(const u16x8*)src;
  u16x8 v1 = *(const u16x8*)(src + 8);
  float hv[16];
#pragma unroll
  for (int e = 0; e < 8; ++e) { hv[e] = bf2f(v0[e]); hv[8 + e] = bf2f(v1[e]); }
  float s0 = 0.f, s1 = 0.f, s2 = 0.f, s3 = 0.f;
#pragma unroll
  for (int e = 0; e < 16; ++e) {
    float h = hv[e];
    s0 += h * W1[woff + e];
    s1 += h * W2[woff + e];
    s2 += h * W3[woff + e];
    s3 += h * W4[woff + e];
  }
#pragma unroll
  for (int off = 32; off >= 1; off >>= 1) {
    s0 += __shfl_xor(s0, off, 64);
    s1 += __shfl_xor(s1, off, 64);
    s2 += __shfl_xor(s2, off, 64);
    s3 += __shfl_xor(s3, off, 64);
  }
  if (lane == 0) {
    out[b * 4 + 0] = sigm(s0 + b1[0]);
    out[b * 4 + 1] = sigm(s1 + b2[0]);
    out[b * 4 + 2] = sigm(s2 + b3[0]);
    out[b * 4 + 3] = sigm(s3 + b4[0]);
  }
}

// ---------------------------------------------------------------------------
extern "C" void kernel_launch(void* const* d_in, const int* in_sizes, int n_in,
                              void* d_out, int out_size, void* d_ws, size_t ws_size,
                              hipStream_t stream) {
  (void)in_sizes; (void)n_in; (void)out_size; (void)ws_size;
  const float* y     = (const float*)d_in[0];
  const float* Wf_ih = (const float*)d_in[1];
  const float* Wf_hh = (const float*)d_in[2];
  const float* bf_ih = (const float*)d_in[3];
  const float* bf_hh = (const float*)d_in[4];
  const float* Wb_ih = (const float*)d_in[5];
  const float* Wb_hh = (const float*)d_in[6];
  const float* bb_ih = (const float*)d_in[7];
  const float* bb_hh = (const float*)d_in[8];
  const float* W1 = (const float*)d_in[9];  const float* b1 = (const float*)d_in[10];
  const float* W2 = (const float*)d_in[11]; const float* b2 = (const float*)d_in[12];
  const float* W3 = (const float*)d_in[13]; const float* b3 = (const float*)d_in[14];
  const float* W4 = (const float*)d_in[15]; const float* b4 = (const float*)d_in[16];

  char* ws = (char*)d_ws;
  const size_t MB = 1ull << 20;
  unsigned short* Wp    = (unsigned short*)(ws);            // 4MB: per-block LDS images
  unsigned short* hf0   = (unsigned short*)(ws + 4 * MB);   // 2MB
  unsigned short* hb0   = (unsigned short*)(ws + 6 * MB);   // 2MB
  unsigned short* hf1   = (unsigned short*)(ws + 8 * MB);   // 2MB
  unsigned short* hb1   = (unsigned short*)(ws + 10 * MB);  // 2MB
  unsigned short* wtail = (unsigned short*)(ws + 12 * MB);  // 64KB
  unsigned* prodf       = (unsigned*)(ws + 13 * MB);        // 256 flags, 128B apart (32KB)

  hipMemsetAsync(ws + 4 * MB, 0, 4 * MB, stream);    // hf0+hb0 = h(t=0) zeros
  hipMemsetAsync(ws + 13 * MB, 0, 32768, stream);    // producer flags

  prep_k<<<1024, 256, 0, stream>>>(Wf_hh, Wf_ih, bf_ih, bf_hh,
                                   Wb_hh, Wb_ih, bb_ih, bb_hh,
                                   Wp, wtail);

  void* args[] = { (void*)&y, (void*)&Wp, (void*)&wtail,
                   (void*)&hf0, (void*)&hf1, (void*)&hb0, (void*)&hb1, (void*)&prodf };
  hipLaunchCooperativeKernel((const void*)lstm_persist, dim3(256), dim3(512),
                             args, 0, stream);

  // 128 steps (even): final h is in buffer 0 for both directions
  heads_k<<<512, 256, 0, stream>>>(hf0, hb0, W1, b1, W2, b2, W3, b3, W4, b4,
                                   (float*)d_out);
}

// Round 5
// 5016.362 us; speedup vs baseline: 2.2234x; 2.2234x over previous
//
#include <hip/hip_runtime.h>

// LSTM_88776974008866: bidirectional LSTM (B=2048, S=128, H=512, in=4) + 4 sigmoid heads.
// Round 5: persistent cooperative kernel; per-slice single-writer dataflow flags
// (NO threadfence — round 4's buffer_wbl2 disaster excised; publish = syncthreads +
// tid0 release store, polls relaxed with s_sleep). Own-slice-first slice order.
// W stationary in LDS (fragment-contiguous, conflict-free); x*Wih+bias folded into a
// tail MFMA (acc init); c in registers; h double-buffered in global (XCD-local L2).

typedef __attribute__((ext_vector_type(8))) __bf16 bf16x8;
typedef __attribute__((ext_vector_type(4))) float f32x4;
typedef __attribute__((ext_vector_type(8))) unsigned short u16x8;

__device__ __forceinline__ unsigned short f2bf(float f) {
  unsigned u = __float_as_uint(f);
  u += 0x7fffu + ((u >> 16) & 1u);   // round-to-nearest-even
  return (unsigned short)(u >> 16);
}
__device__ __forceinline__ float bf2f(unsigned short s) {
  return __uint_as_float(((unsigned)s) << 16);
}
__device__ __forceinline__ float sigm(float x) { return 1.0f / (1.0f + __expf(-x)); }
__device__ __forceinline__ float tanhfast(float x) {
  float e = __expf(-2.0f * fabsf(x));
  float t = (1.0f - e) / (1.0f + e);
  return x < 0.0f ? -t : t;
}

__device__ __forceinline__ void gl_lds16(const void* g, void* l) {
  __builtin_amdgcn_global_load_lds(
      (const __attribute__((address_space(1))) unsigned int*)g,
      (__attribute__((address_space(3))) unsigned int*)l, 16, 0, 0);
}

// ---------------------------------------------------------------------------
// prep: Whh (fp32 [2048][512], gate-major rows i,f,g,o) -> Wp fragment image:
//   chunk = ((((dir*16+ni)*2+wn)*16+kt)*4+nf)*64 + lhi*16 + l15   (16B chunks)
// Also wtail[dir][permrow][8] = {wih[0..3], bias, 0,0,0} bf16 for the tail MFMA.
// ---------------------------------------------------------------------------
__global__ __launch_bounds__(256) void prep_k(
    const float* __restrict__ Wf_hh, const float* __restrict__ Wf_ih,
    const float* __restrict__ bf_ih, const float* __restrict__ bf_hh,
    const float* __restrict__ Wb_hh, const float* __restrict__ Wb_ih,
    const float* __restrict__ bb_ih, const float* __restrict__ bb_hh,
    unsigned short* __restrict__ Wp, unsigned short* __restrict__ wtailp)
{
  int flat = blockIdx.x * 256 + threadIdx.x;   // 0 .. 262143
  int l15 = flat & 15;
  int lhi = (flat >> 4) & 3;
  int nf  = (flat >> 6) & 3;
  int kt  = (flat >> 8) & 15;
  int wn  = (flat >> 12) & 1;
  int ni  = (flat >> 13) & 15;
  int dir = (flat >> 17) & 1;
  const float* Whh = dir ? Wb_hh : Wf_hh;
  const float* Wih = dir ? Wb_ih : Wf_ih;
  const float* bih = dir ? bb_ih : bf_ih;
  const float* bhh = dir ? bb_hh : bf_hh;

  int j = ((ni * 2 + wn) << 4) + l15;          // hidden index 0..511
  int orig = (nf << 9) + j;                    // original gate-major row
  int k0 = (kt << 5) + (lhi << 3);
  const float4* src = (const float4*)(Whh + (size_t)orig * 512 + k0);
  float4 a = src[0], b = src[1];
  u16x8 o;
  o[0] = f2bf(a.x); o[1] = f2bf(a.y); o[2] = f2bf(a.z); o[3] = f2bf(a.w);
  o[4] = f2bf(b.x); o[5] = f2bf(b.y); o[6] = f2bf(b.z); o[7] = f2bf(b.w);
  *(u16x8*)(Wp + (size_t)flat * 8) = o;

  if (kt == 0 && lhi == 0) {
    int rg = (ni << 7) + (wn << 6) + (nf << 4) + l15;   // permuted row
    unsigned short* wt = wtailp + (((size_t)(dir << 11) + rg) << 3);
    wt[0] = f2bf(Wih[orig * 4 + 0]);
    wt[1] = f2bf(Wih[orig * 4 + 1]);
    wt[2] = f2bf(Wih[orig * 4 + 2]);
    wt[3] = f2bf(Wih[orig * 4 + 3]);
    wt[4] = f2bf(bih[orig] + bhh[orig]);
    wt[5] = 0; wt[6] = 0; wt[7] = 0;
  }
}

__device__ __forceinline__ void mfma16(const bf16x8 av[4], const bf16x8 bv[4],
                                       f32x4 acc[4][4]) {
#pragma unroll
  for (int mf = 0; mf < 4; ++mf)
#pragma unroll
    for (int nf = 0; nf < 4; ++nf)
      acc[mf][nf] = __builtin_amdgcn_mfma_f32_16x16x32_bf16(av[mf], bv[nf], acc[mf][nf], 0, 0, 0);
}

// ---------------------------------------------------------------------------
// Persistent kernel: 256 blocks x 512 threads (1 block/CU), all 128 timesteps.
// bid = mi + 8*(dir*16 + ni): xcd = bid%8 = mi, so each (mi,dir) group of 16
// blocks (producers AND consumers of h-panel mi) is XCD-local.
// A k-slice kt (64B chunk of each h row) is produced by group-peer ni==kt;
// consumers poll per-slice single-writer flags, own slice first, no barrier.
// ---------------------------------------------------------------------------
__global__ __launch_bounds__(512, 2) void lstm_persist(
    const float* __restrict__ y,
    const unsigned short* __restrict__ Wp,
    const unsigned short* __restrict__ wtailp,
    unsigned short* __restrict__ hf0, unsigned short* __restrict__ hf1,
    unsigned short* __restrict__ hb0, unsigned short* __restrict__ hb1,
    unsigned* __restrict__ prodf)
{
  __shared__ alignas(16) unsigned short Wl[65536];   // 128 KB W image

  const int tid = threadIdx.x;
  const int w = tid >> 6, lane = tid & 63;
  const int bid = blockIdx.x;
  const int mi = bid & 7;
  const int qd = bid >> 3;
  const int dir = qd >> 4;
  const int ni = qd & 15;
  const int bm0 = mi << 8;                 // 256 batch rows
  const int grp = (dir << 3) | mi;

  unsigned short* h0 = dir ? hb0 : hf0;
  unsigned short* h1 = dir ? hb1 : hf1;

  const int wm = w >> 1;                   // 0..3: 64-row quarter
  const int wn = w & 1;                    // 0..1: 64-col half
  const int l15 = lane & 15;
  const int lhi = lane >> 4;

  // ---- one-time: copy this block's 128KB W image into LDS (contiguous) ----
  const unsigned short* Wblk = Wp + ((size_t)((dir << 4) | ni) << 16);
#pragma unroll
  for (int i = 0; i < 16; ++i) {
    gl_lds16(Wblk + (size_t)(((i << 9) + tid)) * 8,
             (unsigned short*)Wl + ((i << 12) + (w << 9)));
  }

  // ---- tail B-fragments (wih + bias), register-resident ----
  bf16x8 btail[4];
#pragma unroll
  for (int nf = 0; nf < 4; ++nf) {
    u16x8 wt = *(const u16x8*)(wtailp +
        (((size_t)(dir << 11) + ((ni << 7) | (wn << 6) | (nf << 4) | l15))) * 8);
    u16x8 z = {};
    u16x8 sel = (lhi == 0) ? wt : z;
    btail[nf] = *(bf16x8*)&sel;
  }

  const int j = (((ni << 1) + wn) << 4) + l15;   // hidden index 0..511
  float c_reg[16];
#pragma unroll
  for (int i = 0; i < 16; ++i) c_reg[i] = 0.f;

  const float4* y4 = (const float4*)y;
  unsigned* myflag = prodf + (((grp << 4) | ni) << 5);   // 128B-spaced, single writer

  // LDS B-fragment base for this wave (contiguous 1KB per (kt,nf) read)
  const unsigned short* wB = Wl + (wn << 15) + (lane << 3);

  __syncthreads();   // Wl ready (drains global_load_lds)

  const unsigned short* hin = h0;
  unsigned short* hout = h1;

#pragma unroll 1
  for (int t = 0; t < 128; ++t) {
    const int t_eff = dir ? (127 - t) : t;

    // one acquire per step per wave: L1 invalidate so cross-CU h is fresh.
    // (2-step-old buffer lines were already dropped by the previous step's inv.)
    (void)__hip_atomic_load(myflag, __ATOMIC_ACQUIRE, __HIP_MEMORY_SCOPE_AGENT);

    // ---- tail-first: acc = x*Wih + bias (K=32 MFMA, only k=0..4 nonzero) ----
    f32x4 acc[4][4];
#pragma unroll
    for (int a = 0; a < 4; ++a)
#pragma unroll
      for (int b = 0; b < 4; ++b) acc[a][b] = (f32x4){0.f, 0.f, 0.f, 0.f};
    {
      bf16x8 atail[4];
#pragma unroll
      for (int mf = 0; mf < 4; ++mf) {
        float4 x4 = y4[(size_t)(bm0 + (wm << 6) + (mf << 4) + l15) * 128 + t_eff];
        u16x8 at = {};
        if (lhi == 0) {
          at[0] = f2bf(x4.x); at[1] = f2bf(x4.y);
          at[2] = f2bf(x4.z); at[3] = f2bf(x4.w);
          at[4] = 0x3F80;   // 1.0 -> picks up bias row
        }
        atail[mf] = *(bf16x8*)&at;
      }
      mfma16(atail, btail, acc);
    }

    if (t) {   // h(t-1)=0 at t=0: skip the whole GEMM
      const unsigned short* aBase =
          hin + ((size_t)(bm0 + (wm << 6) + l15) << 9) + (lhi << 3);

      bf16x8 aA[2][4], bT[2][4];

#define POLL(kk)                                                               \
      do { if ((kk) != ni) {                                                   \
        const unsigned* fp_ = prodf + (((grp << 4) | (kk)) << 5);              \
        while (__hip_atomic_load(fp_, __ATOMIC_RELAXED,                        \
                                 __HIP_MEMORY_SCOPE_AGENT) < (unsigned)t)      \
          __builtin_amdgcn_s_sleep(1);                                         \
        asm volatile("" ::: "memory");                                         \
      } } while (0)

#define LOADS(kk, sl)                                                          \
      do {                                                                     \
        const unsigned short* ap_ = aBase + ((kk) << 5);                       \
        aA[sl][0] = *(const bf16x8*)(ap_);                                     \
        aA[sl][1] = *(const bf16x8*)(ap_ + (16 << 9));                         \
        aA[sl][2] = *(const bf16x8*)(ap_ + (32 << 9));                         \
        aA[sl][3] = *(const bf16x8*)(ap_ + (48 << 9));                         \
        const unsigned short* bp_ = wB + ((kk) << 11);                         \
        bT[sl][0] = *(const bf16x8*)(bp_);                                     \
        bT[sl][1] = *(const bf16x8*)(bp_ + 512);                               \
        bT[sl][2] = *(const bf16x8*)(bp_ + 1024);                              \
        bT[sl][3] = *(const bf16x8*)(bp_ + 1536);                              \
      } while (0)

      LOADS(ni, 0);   // own slice: no poll needed (published via our own barrier)
#pragma unroll
      for (int i = 0; i < 16; ++i) {
        if (i < 15) {
          const int ktn = (ni + i + 1) & 15;
          POLL(ktn);
          LOADS(ktn, (i + 1) & 1);
        }
        __builtin_amdgcn_s_setprio(1);
        mfma16(aA[i & 1], bT[i & 1], acc);
        __builtin_amdgcn_s_setprio(0);
      }
#undef POLL
#undef LOADS
    }

    // ---- epilogue: lane-local LSTM cell update, c in registers ----
#pragma unroll
    for (int mf = 0; mf < 4; ++mf) {
#pragma unroll
      for (int r = 0; r < 4; ++r) {
        const float ig = sigm(acc[mf][0][r]);
        const float fg = sigm(acc[mf][1][r]);
        const float gg = tanhfast(acc[mf][2][r]);
        const float og = sigm(acc[mf][3][r]);
        const float cn = fg * c_reg[mf * 4 + r] + ig * gg;
        c_reg[mf * 4 + r] = cn;
        const int b = bm0 + (wm << 6) + (mf << 4) + (lhi << 2) + r;
        hout[((size_t)b << 9) + j] = f2bf(og * tanhfast(cn));
      }
    }

    // ---- publish own slice: syncthreads drains stores, tid0 release-store ----
    if (t != 127) {
      __syncthreads();    // compiler emits s_waitcnt vmcnt(0) before s_barrier
      if (tid == 0)
        __hip_atomic_store(myflag, (unsigned)(t + 1), __ATOMIC_RELEASE,
                           __HIP_MEMORY_SCOPE_AGENT);
    }

    const unsigned short* tmp = hin; hin = hout; hout = (unsigned short*)tmp;
  }
}

// ---------------------------------------------------------------------------
// heads: out[b][k] = sigmoid(hf[b]·Wk[0:512] + hb[b]·Wk[512:1024] + bk)
// ---------------------------------------------------------------------------
__global__ __launch_bounds__(256) void heads_k(
    const unsigned short* __restrict__ hf, const unsigned short* __restrict__ hb,
    const float* __restrict__ W1, const float* __restrict__ b1,
    const float* __restrict__ W2, const float* __restrict__ b2,
    const float* __restrict__ W3, const float* __restrict__ b3,
    const float* __restrict__ W4, const float* __restrict__ b4,
    float* __restrict__ out)
{
  const int wid = threadIdx.x >> 6, lane = threadIdx.x & 63;
  const int b = blockIdx.x * 4 + wid;
  const unsigned short* src = (lane < 32) ? (hf + ((size_t)b << 9) + (lane << 4))
                                          : (hb + ((size_t)b << 9) + ((lane - 32) << 4));
  const int woff = lane << 4;
  u16x8 v0 = *(const u16x8*)src;
  u16x8 v1 = *(const u16x8*)(src + 8);
  float hv[16];
#pragma unroll
  for (int e = 0; e < 8; ++e) { hv[e] = bf2f(v0[e]); hv[8 + e] = bf2f(v1[e]); }
  float s0 = 0.f, s1 = 0.f, s2 = 0.f, s3 = 0.f;
#pragma unroll
  for (int e = 0; e < 16; ++e) {
    float h = hv[e];
    s0 += h * W1[woff + e];
    s1 += h * W2[woff + e];
    s2 += h * W3[woff + e];
    s3 += h * W4[woff + e];
  }
#pragma unroll
  for (int off = 32; off >= 1; off >>= 1) {
    s0 += __shfl_xor(s0, off, 64);
    s1 += __shfl_xor(s1, off, 64);
    s2 += __shfl_xor(s2, off, 64);
    s3 += __shfl_xor(s3, off, 64);
  }
  if (lane == 0) {
    out[b * 4 + 0] = sigm(s0 + b1[0]);
    out[b * 4 + 1] = sigm(s1 + b2[0]);
    out[b * 4 + 2] = sigm(s2 + b3[0]);
    out[b * 4 + 3] = sigm(s3 + b4[0]);
  }
}

// ---------------------------------------------------------------------------
extern "C" void kernel_launch(void* const* d_in, const int* in_sizes, int n_in,
                              void* d_out, int out_size, void* d_ws, size_t ws_size,
                              hipStream_t stream) {
  (void)in_sizes; (void)n_in; (void)out_size; (void)ws_size;
  const float* y     = (const float*)d_in[0];
  const float* Wf_ih = (const float*)d_in[1];
  const float* Wf_hh = (const float*)d_in[2];
  const float* bf_ih = (const float*)d_in[3];
  const float* bf_hh = (const float*)d_in[4];
  const float* Wb_ih = (const float*)d_in[5];
  const float* Wb_hh = (const float*)d_in[6];
  const float* bb_ih = (const float*)d_in[7];
  const float* bb_hh = (const float*)d_in[8];
  const float* W1 = (const float*)d_in[9];  const float* b1 = (const float*)d_in[10];
  const float* W2 = (const float*)d_in[11]; const float* b2 = (const float*)d_in[12];
  const float* W3 = (const float*)d_in[13]; const float* b3 = (const float*)d_in[14];
  const float* W4 = (const float*)d_in[15]; const float* b4 = (const float*)d_in[16];

  char* ws = (char*)d_ws;
  const size_t MB = 1ull << 20;
  unsigned short* Wp    = (unsigned short*)(ws);            // 4MB: per-block LDS images
  unsigned short* hf0   = (unsigned short*)(ws + 4 * MB);   // 2MB
  unsigned short* hb0   = (unsigned short*)(ws + 6 * MB);   // 2MB
  unsigned short* hf1   = (unsigned short*)(ws + 8 * MB);   // 2MB
  unsigned short* hb1   = (unsigned short*)(ws + 10 * MB);  // 2MB
  unsigned short* wtail = (unsigned short*)(ws + 12 * MB);  // 64KB
  unsigned* prodf       = (unsigned*)(ws + 13 * MB);        // 256 flags, 128B apart (32KB)

  hipMemsetAsync(ws + 4 * MB, 0, 4 * MB, stream);    // hf0+hb0 = h(t=0) zeros
  hipMemsetAsync(ws + 13 * MB, 0, 32768, stream);    // producer flags

  prep_k<<<1024, 256, 0, stream>>>(Wf_hh, Wf_ih, bf_ih, bf_hh,
                                   Wb_hh, Wb_ih, bb_ih, bb_hh,
                                   Wp, wtail);

  void* args[] = { (void*)&y, (void*)&Wp, (void*)&wtail,
                   (void*)&hf0, (void*)&hf1, (void*)&hb0, (void*)&hb1, (void*)&prodf };
  hipLaunchCooperativeKernel((const void*)lstm_persist, dim3(256), dim3(512),
                             args, 0, stream);

  // 128 steps (even): final h is in buffer 0 for both directions
  heads_k<<<512, 256, 0, stream>>>(hf0, hb0, W1, b1, W2, b2, W3, b3, W4, b4,
                                   (float*)d_out);
}

// Round 6
// 4923.305 us; speedup vs baseline: 2.2655x; 1.0189x over previous
//
#include <hip/hip_runtime.h>

// LSTM_88776974008866: bidirectional LSTM (B=2048, S=128, H=512, in=4) + 4 sigmoid heads.
// Round 6: persistent cooperative kernel, wave-decoupled group sync.
//  - publish via agent ACQ_REL fetch_add (r3-proven: no L2 flush). NEVER a release store
//    (r4/r5: agent release store -> buffer_wbl2 -> 525MB HBM writes).
//  - no __syncthreads in the step loop: per-wave vmcnt(0) drain + LDS arrival counter,
//    8th wave publishes; every wave polls the single group flag once per step.
//  - depth-3 register A prefetch, depth-2 B (LDS), fully unrolled static ring.
//  - W stationary in LDS (fragment-contiguous, conflict-free); x*Wih+bias folded into
//    a tail MFMA; c in registers; h double-buffered in global (XCD-local L2).

typedef __attribute__((ext_vector_type(8))) __bf16 bf16x8;
typedef __attribute__((ext_vector_type(4))) float f32x4;
typedef __attribute__((ext_vector_type(8))) unsigned short u16x8;

__device__ __forceinline__ unsigned short f2bf(float f) {
  unsigned u = __float_as_uint(f);
  u += 0x7fffu + ((u >> 16) & 1u);   // round-to-nearest-even
  return (unsigned short)(u >> 16);
}
__device__ __forceinline__ float bf2f(unsigned short s) {
  return __uint_as_float(((unsigned)s) << 16);
}
__device__ __forceinline__ float sigm(float x) { return 1.0f / (1.0f + __expf(-x)); }
__device__ __forceinline__ float tanhfast(float x) {
  float e = __expf(-2.0f * fabsf(x));
  float t = (1.0f - e) / (1.0f + e);
  return x < 0.0f ? -t : t;
}

__device__ __forceinline__ void gl_lds16(const void* g, void* l) {
  __builtin_amdgcn_global_load_lds(
      (const __attribute__((address_space(1))) unsigned int*)g,
      (__attribute__((address_space(3))) unsigned int*)l, 16, 0, 0);
}

// ---------------------------------------------------------------------------
// prep: Whh (fp32 [2048][512], gate-major rows i,f,g,o) -> Wp fragment image:
//   chunk = ((((dir*16+ni)*2+wn)*16+kt)*4+nf)*64 + lhi*16 + l15   (16B chunks)
// Also wtail[dir][permrow][8] = {wih[0..3], bias, 0,0,0} bf16 for the tail MFMA.
// ---------------------------------------------------------------------------
__global__ __launch_bounds__(256) void prep_k(
    const float* __restrict__ Wf_hh, const float* __restrict__ Wf_ih,
    const float* __restrict__ bf_ih, const float* __restrict__ bf_hh,
    const float* __restrict__ Wb_hh, const float* __restrict__ Wb_ih,
    const float* __restrict__ bb_ih, const float* __restrict__ bb_hh,
    unsigned short* __restrict__ Wp, unsigned short* __restrict__ wtailp)
{
  int flat = blockIdx.x * 256 + threadIdx.x;   // 0 .. 262143
  int l15 = flat & 15;
  int lhi = (flat >> 4) & 3;
  int nf  = (flat >> 6) & 3;
  int kt  = (flat >> 8) & 15;
  int wn  = (flat >> 12) & 1;
  int ni  = (flat >> 13) & 15;
  int dir = (flat >> 17) & 1;
  const float* Whh = dir ? Wb_hh : Wf_hh;
  const float* Wih = dir ? Wb_ih : Wf_ih;
  const float* bih = dir ? bb_ih : bf_ih;
  const float* bhh = dir ? bb_hh : bf_hh;

  int j = ((ni * 2 + wn) << 4) + l15;          // hidden index 0..511
  int orig = (nf << 9) + j;                    // original gate-major row
  int k0 = (kt << 5) + (lhi << 3);
  const float4* src = (const float4*)(Whh + (size_t)orig * 512 + k0);
  float4 a = src[0], b = src[1];
  u16x8 o;
  o[0] = f2bf(a.x); o[1] = f2bf(a.y); o[2] = f2bf(a.z); o[3] = f2bf(a.w);
  o[4] = f2bf(b.x); o[5] = f2bf(b.y); o[6] = f2bf(b.z); o[7] = f2bf(b.w);
  *(u16x8*)(Wp + (size_t)flat * 8) = o;

  if (kt == 0 && lhi == 0) {
    int rg = (ni << 7) + (wn << 6) + (nf << 4) + l15;   // permuted row
    unsigned short* wt = wtailp + (((size_t)(dir << 11) + rg) << 3);
    wt[0] = f2bf(Wih[orig * 4 + 0]);
    wt[1] = f2bf(Wih[orig * 4 + 1]);
    wt[2] = f2bf(Wih[orig * 4 + 2]);
    wt[3] = f2bf(Wih[orig * 4 + 3]);
    wt[4] = f2bf(bih[orig] + bhh[orig]);
    wt[5] = 0; wt[6] = 0; wt[7] = 0;
  }
}

__device__ __forceinline__ void mfma16(const bf16x8 av[4], const bf16x8 bv[4],
                                       f32x4 acc[4][4]) {
#pragma unroll
  for (int mf = 0; mf < 4; ++mf)
#pragma unroll
    for (int nf = 0; nf < 4; ++nf)
      acc[mf][nf] = __builtin_amdgcn_mfma_f32_16x16x32_bf16(av[mf], bv[nf], acc[mf][nf], 0, 0, 0);
}

// ---------------------------------------------------------------------------
// Persistent kernel: 256 blocks x 512 threads (1 block/CU), all 128 timesteps.
// bid = mi + 8*(dir*16 + ni): xcd = bid%8 = mi, so each (mi,dir) group of 16
// blocks (producers AND consumers of h-panel mi) is XCD-local.
// Sync per step: each wave drains vmcnt(0), lane0 bumps LDS arrival counter;
// the 8th wave fetch_adds (ACQ_REL, agent) the group flag. Every wave polls the
// flag (relaxed + one acquire) at step top. No __syncthreads in the loop.
// ---------------------------------------------------------------------------
__global__ __launch_bounds__(512, 2) void lstm_persist(
    const float* __restrict__ y,
    const unsigned short* __restrict__ Wp,
    const unsigned short* __restrict__ wtailp,
    unsigned short* __restrict__ hf0, unsigned short* __restrict__ hf1,
    unsigned short* __restrict__ hb0, unsigned short* __restrict__ hb1,
    unsigned* __restrict__ prodf)
{
  __shared__ alignas(16) unsigned short Wl[65536];   // 128 KB W image
  __shared__ unsigned arrive_cnt;

  const int tid = threadIdx.x;
  const int w = tid >> 6, lane = tid & 63;
  const int bid = blockIdx.x;
  const int mi = bid & 7;
  const int qd = bid >> 3;
  const int dir = qd >> 4;
  const int ni = qd & 15;
  const int bm0 = mi << 8;                 // 256 batch rows
  const int grp = (dir << 3) | mi;

  unsigned short* h0 = dir ? hb0 : hf0;
  unsigned short* h1 = dir ? hb1 : hf1;

  const int wm = w >> 1;                   // 0..3: 64-row quarter
  const int wn = w & 1;                    // 0..1: 64-col half
  const int l15 = lane & 15;
  const int lhi = lane >> 4;

  if (tid == 0) arrive_cnt = 0u;

  // ---- one-time: copy this block's 128KB W image into LDS (contiguous) ----
  const unsigned short* Wblk = Wp + ((size_t)((dir << 4) | ni) << 16);
#pragma unroll
  for (int i = 0; i < 16; ++i) {
    gl_lds16(Wblk + (size_t)(((i << 9) + tid)) * 8,
             (unsigned short*)Wl + ((i << 12) + (w << 9)));
  }

  // ---- tail B-fragments (wih + bias), register-resident ----
  bf16x8 btail[4];
#pragma unroll
  for (int nf = 0; nf < 4; ++nf) {
    u16x8 wt = *(const u16x8*)(wtailp +
        (((size_t)(dir << 11) + ((ni << 7) | (wn << 6) | (nf << 4) | l15))) * 8);
    u16x8 z = {};
    u16x8 sel = (lhi == 0) ? wt : z;
    btail[nf] = *(bf16x8*)&sel;
  }

  const int j = (((ni << 1) + wn) << 4) + l15;   // hidden index 0..511
  float c_reg[16];
#pragma unroll
  for (int i = 0; i < 16; ++i) c_reg[i] = 0.f;

  const float4* y4 = (const float4*)y;
  unsigned* gflag = prodf + (grp << 5);          // one flag per group, 128B apart

  // LDS B-fragment base for this wave (contiguous 1KB per (kt,nf) read)
  const unsigned short* wB = Wl + (wn << 15) + (lane << 3);

  __syncthreads();   // Wl + arrive_cnt ready (drains global_load_lds)

  const unsigned short* hin = h0;
  unsigned short* hout = h1;

#pragma unroll 1
  for (int t = 0; t < 128; ++t) {
    const int t_eff = dir ? (127 - t) : t;

    // ---- x loads first (independent of the flag) ----
    float4 xr[4];
#pragma unroll
    for (int mf = 0; mf < 4; ++mf)
      xr[mf] = y4[(size_t)(bm0 + (wm << 6) + (mf << 4) + l15) * 128 + t_eff];

    // ---- wait for all group peers to have finished step t-1 ----
    if (t) {
      const unsigned tgt = (unsigned)(t << 4);   // 16*t cumulative publishes
      while (__hip_atomic_load(gflag, __ATOMIC_RELAXED, __HIP_MEMORY_SCOPE_AGENT) < tgt)
        __builtin_amdgcn_s_sleep(1);
      (void)__hip_atomic_load(gflag, __ATOMIC_ACQUIRE, __HIP_MEMORY_SCOPE_AGENT);
      asm volatile("" ::: "memory");
    }

    f32x4 acc[4][4];
#pragma unroll
    for (int a = 0; a < 4; ++a)
#pragma unroll
      for (int b = 0; b < 4; ++b) acc[a][b] = (f32x4){0.f, 0.f, 0.f, 0.f};

    if (t) {
      const unsigned short* aBase =
          hin + ((size_t)(bm0 + (wm << 6) + l15) << 9) + (lhi << 3);

      bf16x8 aA[3][4], bT[2][4];

#define ALOAD(kk, sl)                                                          \
      do {                                                                     \
        const unsigned short* ap_ = aBase + ((kk) << 5);                       \
        aA[sl][0] = *(const bf16x8*)(ap_);                                     \
        aA[sl][1] = *(const bf16x8*)(ap_ + (16 << 9));                         \
        aA[sl][2] = *(const bf16x8*)(ap_ + (32 << 9));                         \
        aA[sl][3] = *(const bf16x8*)(ap_ + (48 << 9));                         \
      } while (0)
#define BLOAD(kk, sl)                                                          \
      do {                                                                     \
        const unsigned short* bp_ = wB + ((kk) << 11);                         \
        bT[sl][0] = *(const bf16x8*)(bp_);                                     \
        bT[sl][1] = *(const bf16x8*)(bp_ + 512);                               \
        bT[sl][2] = *(const bf16x8*)(bp_ + 1024);                              \
        bT[sl][3] = *(const bf16x8*)(bp_ + 1536);                              \
      } while (0)

      // prologue: A slices 0..2, B slices 0..1
      ALOAD(0, 0); ALOAD(1, 1); ALOAD(2, 2);
      BLOAD(0, 0); BLOAD(1, 1);

      // tail MFMA while prologue loads are in flight
      {
        bf16x8 atail[4];
#pragma unroll
        for (int mf = 0; mf < 4; ++mf) {
          u16x8 at = {};
          if (lhi == 0) {
            at[0] = f2bf(xr[mf].x); at[1] = f2bf(xr[mf].y);
            at[2] = f2bf(xr[mf].z); at[3] = f2bf(xr[mf].w);
            at[4] = 0x3F80;   // 1.0 -> picks up bias row
          }
          atail[mf] = *(bf16x8*)&at;
        }
        mfma16(atail, btail, acc);
      }

#pragma unroll
      for (int i = 0; i < 16; ++i) {
        __builtin_amdgcn_s_setprio(1);
        mfma16(aA[i % 3], bT[i & 1], acc);
        __builtin_amdgcn_s_setprio(0);
        if (i < 13) ALOAD(i + 3, (i + 3) % 3);
        if (i < 14) BLOAD(i + 2, i & 1);
      }
#undef ALOAD
#undef BLOAD
    } else {
      // t=0: h=0, GEMM skipped; just tail
      bf16x8 atail[4];
#pragma unroll
      for (int mf = 0; mf < 4; ++mf) {
        u16x8 at = {};
        if (lhi == 0) {
          at[0] = f2bf(xr[mf].x); at[1] = f2bf(xr[mf].y);
          at[2] = f2bf(xr[mf].z); at[3] = f2bf(xr[mf].w);
          at[4] = 0x3F80;
        }
        atail[mf] = *(bf16x8*)&at;
      }
      mfma16(atail, btail, acc);
    }

    // ---- epilogue: lane-local LSTM cell update, c in registers ----
#pragma unroll
    for (int mf = 0; mf < 4; ++mf) {
#pragma unroll
      for (int r = 0; r < 4; ++r) {
        const float ig = sigm(acc[mf][0][r]);
        const float fg = sigm(acc[mf][1][r]);
        const float gg = tanhfast(acc[mf][2][r]);
        const float og = sigm(acc[mf][3][r]);
        const float cn = fg * c_reg[mf * 4 + r] + ig * gg;
        c_reg[mf * 4 + r] = cn;
        const int b = bm0 + (wm << 6) + (mf << 4) + (lhi << 2) + r;
        hout[((size_t)b << 9) + j] = f2bf(og * tanhfast(cn));
      }
    }

    // ---- publish: per-wave store drain + LDS arrival; 8th wave does group RMW ----
    if (t != 127) {
      asm volatile("s_waitcnt vmcnt(0)" ::: "memory");   // own h stores in L2
      if (lane == 0) {
        unsigned old = atomicAdd(&arrive_cnt, 1u);       // ds_add_rtn, intra-block
        if (old == (unsigned)((t << 3) + 7)) {           // last of 8 waves this step
          __hip_atomic_fetch_add(gflag, 1u, __ATOMIC_ACQ_REL,
                                 __HIP_MEMORY_SCOPE_AGENT);
        }
      }
    }

    const unsigned short* tmp = hin; hin = hout; hout = (unsigned short*)tmp;
  }
}

// ---------------------------------------------------------------------------
// heads: out[b][k] = sigmoid(hf[b]·Wk[0:512] + hb[b]·Wk[512:1024] + bk)
// ---------------------------------------------------------------------------
__global__ __launch_bounds__(256) void heads_k(
    const unsigned short* __restrict__ hf, const unsigned short* __restrict__ hb,
    const float* __restrict__ W1, const float* __restrict__ b1,
    const float* __restrict__ W2, const float* __restrict__ b2,
    const float* __restrict__ W3, const float* __restrict__ b3,
    const float* __restrict__ W4, const float* __restrict__ b4,
    float* __restrict__ out)
{
  const int wid = threadIdx.x >> 6, lane = threadIdx.x & 63;
  const int b = blockIdx.x * 4 + wid;
  const unsigned short* src = (lane < 32) ? (hf + ((size_t)b << 9) + (lane << 4))
                                          : (hb + ((size_t)b << 9) + ((lane - 32) << 4));
  const int woff = lane << 4;
  u16x8 v0 = *(const u16x8*)src;
  u16x8 v1 = *(const u16x8*)(src + 8);
  float hv[16];
#pragma unroll
  for (int e = 0; e < 8; ++e) { hv[e] = bf2f(v0[e]); hv[8 + e] = bf2f(v1[e]); }
  float s0 = 0.f, s1 = 0.f, s2 = 0.f, s3 = 0.f;
#pragma unroll
  for (int e = 0; e < 16; ++e) {
    float h = hv[e];
    s0 += h * W1[woff + e];
    s1 += h * W2[woff + e];
    s2 += h * W3[woff + e];
    s3 += h * W4[woff + e];
  }
#pragma unroll
  for (int off = 32; off >= 1; off >>= 1) {
    s0 += __shfl_xor(s0, off, 64);
    s1 += __shfl_xor(s1, off, 64);
    s2 += __shfl_xor(s2, off, 64);
    s3 += __shfl_xor(s3, off, 64);
  }
  if (lane == 0) {
    out[b * 4 + 0] = sigm(s0 + b1[0]);
    out[b * 4 + 1] = sigm(s1 + b2[0]);
    out[b * 4 + 2] = sigm(s2 + b3[0]);
    out[b * 4 + 3] = sigm(s3 + b4[0]);
  }
}

// ---------------------------------------------------------------------------
extern "C" void kernel_launch(void* const* d_in, const int* in_sizes, int n_in,
                              void* d_out, int out_size, void* d_ws, size_t ws_size,
                              hipStream_t stream) {
  (void)in_sizes; (void)n_in; (void)out_size; (void)ws_size;
  const float* y     = (const float*)d_in[0];
  const float* Wf_ih = (const float*)d_in[1];
  const float* Wf_hh = (const float*)d_in[2];
  const float* bf_ih = (const float*)d_in[3];
  const float* bf_hh = (const float*)d_in[4];
  const float* Wb_ih = (const float*)d_in[5];
  const float* Wb_hh = (const float*)d_in[6];
  const float* bb_ih = (const float*)d_in[7];
  const float* bb_hh = (const float*)d_in[8];
  const float* W1 = (const float*)d_in[9];  const float* b1 = (const float*)d_in[10];
  const float* W2 = (const float*)d_in[11]; const float* b2 = (const float*)d_in[12];
  const float* W3 = (const float*)d_in[13]; const float* b3 = (const float*)d_in[14];
  const float* W4 = (const float*)d_in[15]; const float* b4 = (const float*)d_in[16];

  char* ws = (char*)d_ws;
  const size_t MB = 1ull << 20;
  unsigned short* Wp    = (unsigned short*)(ws);            // 4MB: per-block LDS images
  unsigned short* hf0   = (unsigned short*)(ws + 4 * MB);   // 2MB
  unsigned short* hb0   = (unsigned short*)(ws + 6 * MB);   // 2MB
  unsigned short* hf1   = (unsigned short*)(ws + 8 * MB);   // 2MB
  unsigned short* hb1   = (unsigned short*)(ws + 10 * MB);  // 2MB
  unsigned short* wtail = (unsigned short*)(ws + 12 * MB);  // 64KB
  unsigned* prodf       = (unsigned*)(ws + 13 * MB);        // 16 group flags, 128B apart

  hipMemsetAsync(ws + 4 * MB, 0, 4 * MB, stream);    // hf0+hb0 = h(t=0) zeros
  hipMemsetAsync(ws + 13 * MB, 0, 4096, stream);     // group flags

  prep_k<<<1024, 256, 0, stream>>>(Wf_hh, Wf_ih, bf_ih, bf_hh,
                                   Wb_hh, Wb_ih, bb_ih, bb_hh,
                                   Wp, wtail);

  void* args[] = { (void*)&y, (void*)&Wp, (void*)&wtail,
                   (void*)&hf0, (void*)&hf1, (void*)&hb0, (void*)&hb1, (void*)&prodf };
  hipLaunchCooperativeKernel((const void*)lstm_persist, dim3(256), dim3(512),
                             args, 0, stream);

  // 128 steps (even): final h is in buffer 0 for both directions
  heads_k<<<512, 256, 0, stream>>>(hf0, hb0, W1, b1, W2, b2, W3, b3, W4, b4,
                                   (float*)d_out);
}